// Round 6
// baseline (280.340 us; speedup 1.0000x reference)
//
#include <hip/hip_runtime.h>
#include <math.h>

#define DD 768
#define DD4 192
#define KK 16
#define EPSV 1e-5f

// DPP helpers. quad_perm 0xB1 = lane^1, 0x4E = lane^2, row_half_mirror 0x141
// = lane^7 (within 8), row_mirror 0x140 = lane^15 (within 16).
template <int CTRL>
__device__ __forceinline__ float dpp_addf(float v) {
    int t = __builtin_amdgcn_update_dpp(0, __float_as_int(v), CTRL, 0xF, 0xF, true);
    return v + __int_as_float(t);
}
template <int CTRL>
__device__ __forceinline__ int dpp_movi(int v) {
    return __builtin_amdgcn_update_dpp(0, v, CTRL, 0xF, 0xF, true);
}
#define DPP_XOR1 0xB1
#define DPP_XOR2 0x4E
#define DPP_HMIR 0x141

__device__ __forceinline__ float red8(float v) {
    v = dpp_addf<DPP_XOR1>(v);
    v = dpp_addf<DPP_XOR2>(v);
    v = dpp_addf<DPP_HMIR>(v);
    return v;   // 8-lane-group sum in every lane of the group
}

// argmin combine step over xor-partner CTRL (min val, tie -> lower idx)
template <int CTRL>
__device__ __forceinline__ void amin_step(float& sq, int& idx) {
    float osq = __int_as_float(dpp_movi<CTRL>(__float_as_int(sq)));
    int   oidx = dpp_movi<CTRL>(idx);
    bool take = (osq < sq) || (osq == sq && oidx < idx);
    sq  = take ? osq  : sq;
    idx = take ? oidx : idx;
}

typedef float nfloat4 __attribute__((ext_vector_type(4)));
__device__ __forceinline__ float4 ntload4(const float4* p) {
    nfloat4 v = __builtin_nontemporal_load((const nfloat4*)p);
    return make_float4(v.x, v.y, v.z, v.w);
}
__device__ __forceinline__ void ntstore4(float4* p, float4 v) {
    nfloat4 t = {v.x, v.y, v.z, v.w};
    __builtin_nontemporal_store(t, (nfloat4*)p);
}

// One wave = 4 rows (one "group"). K split into two passes of 8 -> dot accs
// stay at 32 VGPRs and transpose scratch stays [8][40] per wave.
// LDS = 49152 + 5120 = 54272 B -> 3 blocks/CU.
__global__ __launch_bounds__(256, 3)
void sln_kernel(const float* __restrict__ x,
                const float* __restrict__ weights,
                const float* __restrict__ biases,
                const float* __restrict__ centroids,
                float* __restrict__ out,
                float* __restrict__ bkt,
                int nrows)
{
    __shared__ float cs[KK * DD];        // 48 KB centroids
    __shared__ float scr[4][8][40];      // 5 KB per-wave transpose scratch

    const int tid  = threadIdx.x;
    const int lane = tid & 63;
    const int wave = tid >> 6;

    // stage centroids (coalesced float4)
    {
        const float4* c4 = (const float4*)centroids;
        float4* cs4w = (float4*)cs;
        for (int i = tid; i < KK * DD4; i += 256) cs4w[i] = c4[i];
    }
    __syncthreads();

    // c2[k] via block-wide partials (scr reused as flat scratch)
    float* flat = &scr[0][0][0];
    {
        int k = tid >> 4, t = tid & 15;
        float p = 0.f;
        #pragma unroll
        for (int j = 0; j < DD / 16; ++j) {
            float v = cs[k * DD + t + 16 * j];
            p += v * v;
        }
        flat[tid] = p;
    }
    __syncthreads();
    if (tid < KK) {
        float sacc = 0.f;
        #pragma unroll
        for (int i = 0; i < 16; ++i) sacc += flat[tid * 16 + i];
        flat[256 + tid] = sacc;
    }
    __syncthreads();
    const float c2A = flat[256 + (lane & 7)];      // c2[lane&7]
    const float c2B = flat[264 + (lane & 7)];      // c2[8 + (lane&7)]
    __syncthreads();                               // scr reused below

    const float4* cs4 = (const float4*)cs;
    const int ngroups = nrows >> 2;
    const int gw = blockIdx.x * 4 + wave;
    const int wstride = gridDim.x * 4;

    for (int grp = gw; grp < ngroups; grp += wstride) {
        const int r0 = grp * 4;
        const float4* xp = (const float4*)(x + (size_t)r0 * DD);

        float4 a[4][3];
        #pragma unroll
        for (int r = 0; r < 4; ++r) {
            a[r][0] = ntload4(xp + r * DD4 + lane);
            a[r][1] = ntload4(xp + r * DD4 + lane + 64);
            a[r][2] = ntload4(xp + r * DD4 + lane + 128);
        }

        float s[4], ss[4];
        #pragma unroll
        for (int r = 0; r < 4; ++r) {
            float4 p = a[r][0], q = a[r][1], w = a[r][2];
            s[r]  = p.x+p.y+p.z+p.w + q.x+q.y+q.z+q.w + w.x+w.y+w.z+w.w;
            ss[r] = p.x*p.x+p.y*p.y+p.z*p.z+p.w*p.w
                  + q.x*q.x+q.y*q.y+q.z*q.z+q.w*q.w
                  + w.x*w.x+w.y*w.y+w.z*w.z+w.w*w.w;
        }

        // ---- pass A: k = 0..7 ----
        float dA[4][8];
        #pragma unroll
        for (int k = 0; k < 8; ++k) {
            float4 c0 = cs4[k * DD4 + lane];
            float4 c1 = cs4[k * DD4 + lane + 64];
            float4 c2v = cs4[k * DD4 + lane + 128];
            #pragma unroll
            for (int r = 0; r < 4; ++r) {
                dA[r][k] = a[r][0].x*c0.x + a[r][0].y*c0.y + a[r][0].z*c0.z + a[r][0].w*c0.w
                         + a[r][1].x*c1.x + a[r][1].y*c1.y + a[r][1].z*c1.z + a[r][1].w*c1.w
                         + a[r][2].x*c2v.x + a[r][2].y*c2v.y + a[r][2].z*c2v.z + a[r][2].w*c2v.w;
            }
        }
        #pragma unroll
        for (int r = 0; r < 4; ++r)
            #pragma unroll
            for (int k = 0; k < 8; ++k) dA[r][k] = red8(dA[r][k]);

        if ((lane & 7) == 0) {
            int g = lane >> 3;
            float4* p4 = (float4*)&scr[wave][g][0];
            #pragma unroll
            for (int r = 0; r < 4; ++r) {
                p4[2*r]   = make_float4(dA[r][0], dA[r][1], dA[r][2], dA[r][3]);
                p4[2*r+1] = make_float4(dA[r][4], dA[r][5], dA[r][6], dA[r][7]);
            }
        }
        __asm__ volatile("" ::: "memory");

        // read A: lane L<32 -> slot L = row(L>>3), kA(L&7)
        float TA = 0.f;
        if (lane < 32) {
            float t0 = scr[wave][0][lane] + scr[wave][4][lane];
            float t1 = scr[wave][1][lane] + scr[wave][5][lane];
            float t2 = scr[wave][2][lane] + scr[wave][6][lane];
            float t3 = scr[wave][3][lane] + scr[wave][7][lane];
            TA = (t0 + t1) + (t2 + t3);
        }
        __asm__ volatile("" ::: "memory");

        // ---- pass B: k = 8..15 + s/ss ----
        float dB[4][8];
        #pragma unroll
        for (int k = 0; k < 8; ++k) {
            float4 c0 = cs4[(k + 8) * DD4 + lane];
            float4 c1 = cs4[(k + 8) * DD4 + lane + 64];
            float4 c2v = cs4[(k + 8) * DD4 + lane + 128];
            #pragma unroll
            for (int r = 0; r < 4; ++r) {
                dB[r][k] = a[r][0].x*c0.x + a[r][0].y*c0.y + a[r][0].z*c0.z + a[r][0].w*c0.w
                         + a[r][1].x*c1.x + a[r][1].y*c1.y + a[r][1].z*c1.z + a[r][1].w*c1.w
                         + a[r][2].x*c2v.x + a[r][2].y*c2v.y + a[r][2].z*c2v.z + a[r][2].w*c2v.w;
            }
        }
        #pragma unroll
        for (int r = 0; r < 4; ++r) {
            #pragma unroll
            for (int k = 0; k < 8; ++k) dB[r][k] = red8(dB[r][k]);
            s[r] = red8(s[r]);
            ss[r] = red8(ss[r]);
        }

        if ((lane & 7) == 0) {
            int g = lane >> 3;
            float4* p4 = (float4*)&scr[wave][g][0];
            #pragma unroll
            for (int r = 0; r < 4; ++r) {
                p4[2*r]   = make_float4(dB[r][0], dB[r][1], dB[r][2], dB[r][3]);
                p4[2*r+1] = make_float4(dB[r][4], dB[r][5], dB[r][6], dB[r][7]);
            }
            p4[8] = make_float4(s[0], ss[0], s[1], ss[1]);
            p4[9] = make_float4(s[2], ss[2], s[3], ss[3]);
        }
        __asm__ volatile("" ::: "memory");

        // read B: lane<32 -> dots k=8..15; lanes 32..39 -> s/ss
        float TB = 0.f;
        if (lane < 40) {
            float t0 = scr[wave][0][lane] + scr[wave][4][lane];
            float t1 = scr[wave][1][lane] + scr[wave][5][lane];
            float t2 = scr[wave][2][lane] + scr[wave][6][lane];
            float t3 = scr[wave][3][lane] + scr[wave][7][lane];
            TB = (t0 + t1) + (t2 + t3);
        }
        __asm__ volatile("" ::: "memory");

        // broadcast per-row sums (SGPR)
        float sV[4], ssV[4];
        #pragma unroll
        for (int r = 0; r < 4; ++r) {
            sV[r]  = __int_as_float(__builtin_amdgcn_readlane(__float_as_int(TB), 32 + 2*r));
            ssV[r] = __int_as_float(__builtin_amdgcn_readlane(__float_as_int(TB), 33 + 2*r));
        }

        // per-lane dists: row = (lane>>3)&3 (valid for lane<32), kA=lane&7, kB=8+(lane&7)
        float ssSel = (lane & 16) ? ((lane & 8) ? ssV[3] : ssV[2])
                                  : ((lane & 8) ? ssV[1] : ssV[0]);
        float sqA = (ssSel - 2.f * TA) + c2A;
        float sqB = (ssSel - 2.f * TB) + c2B;
        bool tb = (sqB < sqA);            // tie -> kA (lower index)
        float sq = tb ? sqB : sqA;
        int  idx = tb ? (8 + (lane & 7)) : (lane & 7);
        amin_step<DPP_XOR1>(sq, idx);
        amin_step<DPP_XOR2>(sq, idx);
        amin_step<DPP_HMIR>(sq, idx);

        const int bks0 = __builtin_amdgcn_readlane(idx, 0);
        const int bks1 = __builtin_amdgcn_readlane(idx, 8);
        const int bks2 = __builtin_amdgcn_readlane(idx, 16);
        const int bks3 = __builtin_amdgcn_readlane(idx, 24);
        const int bks[4] = {bks0, bks1, bks2, bks3};

        if (lane == 0) {
            float4* bp = (float4*)(bkt + r0);   // r0 % 4 == 0 -> aligned
            *bp = make_float4((float)bks0, (float)bks1, (float)bks2, (float)bks3);
        }

        #pragma unroll
        for (int r = 0; r < 4; ++r) {
            const float4* wp = (const float4*)(weights + (size_t)bks[r] * DD);
            const float4* gp = (const float4*)(biases  + (size_t)bks[r] * DD);
            float4* op = (float4*)(out + (size_t)(r0 + r) * DD);
            const float mr = sV[r] * (1.f / DD);
            const float rs = 1.f / sqrtf(ssV[r] * (1.f / DD) - mr * mr + EPSV);
            #pragma unroll
            for (int j = 0; j < 3; ++j) {
                float4 wv = wp[lane + 64 * j];
                float4 bv = gp[lane + 64 * j];
                float4 xv = a[r][j];
                float4 o;
                o.x = (xv.x - mr) * rs * wv.x + bv.x;
                o.y = (xv.y - mr) * rs * wv.y + bv.y;
                o.z = (xv.z - mr) * rs * wv.z + bv.z;
                o.w = (xv.w - mr) * rs * wv.w + bv.w;
                ntstore4(op + lane + 64 * j, o);
            }
        }
    }
}

extern "C" void kernel_launch(void* const* d_in, const int* in_sizes, int n_in,
                              void* d_out, int out_size, void* d_ws, size_t ws_size,
                              hipStream_t stream) {
    const float* x         = (const float*)d_in[0];
    const float* weights   = (const float*)d_in[1];
    const float* biases    = (const float*)d_in[2];
    const float* centroids = (const float*)d_in[3];

    const int nrows = in_sizes[0] / DD;   // 32768

    float* out = (float*)d_out;
    float* bkt = out + (size_t)nrows * DD;

    dim3 grid(2048), block(256);   // 8192 waves = nrows/4 groups exactly
    hipLaunchKernelGGL(sln_kernel, grid, block, 0, stream,
                       x, weights, biases, centroids, out, bkt, nrows);
}